// Round 7
// baseline (232.027 us; speedup 1.0000x reference)
//
#include <hip/hip_runtime.h>
#include <hip/hip_bf16.h>
#include <math.h>

// ---------------------------------------------------------------------------
// GraphSAGE inference, bf16 MFMA pipeline.
//   h1 = relu([aggr(x)|x] @ [w1l;w1r] + b1)      (MFMA, K=256)
//   h2 = relu([aggr(h1)|h1] @ [w2l;w2r] + b2)
//   out = log_softmax(mean_pool(h2) @ wf + bf)
// R1: atomics -> CSR+gather. R2: bf16 MFMA GEMM, packed weights.
// R3: gather MLP. R4: atomic-free localized CSR fill. R5: segmented pool.
// R6: fused gather+GEMM layer kernel (per-wave LDS tile, no barrier),
//     2-node interleaved gather (2x in-flight), merged prep kernel.
// ---------------------------------------------------------------------------

#define FDIM 128

typedef __attribute__((ext_vector_type(8))) short bf16x8;
typedef __attribute__((ext_vector_type(4))) float f32x4;

__device__ inline unsigned short f2bf(float f) {
    union { float f; unsigned u; } v; v.f = f;
    unsigned r = v.u + 0x7fff + ((v.u >> 16) & 1);   // RNE
    return (unsigned short)(r >> 16);
}
__device__ inline float bf2f(unsigned short b) {
    union { unsigned u; float f; } v; v.u = ((unsigned)b) << 16;
    return v.f;
}

// --- merged prep: deg+rank | f32->bf16 cvt | weight packs -------------------
// blocks [0,nbE): rank[e]=atomicAdd(deg[dst[e]],1)
// blocks [nbE,nbE+nbC): xb = bf16(x), 4 elems/thread
// blocks [nbE+nbC, +32): pack wp1 (16 blocks) and wp2 (16 blocks)
__global__ __launch_bounds__(256) void prep_k(
        const int* __restrict__ dst, int* __restrict__ deg, int* __restrict__ rank, int nE,
        const float* __restrict__ x, unsigned short* __restrict__ xb, int n4,
        const float* __restrict__ w1l, const float* __restrict__ w1r,
        unsigned short* __restrict__ wp1,
        const float* __restrict__ w2l, const float* __restrict__ w2r,
        unsigned short* __restrict__ wp2,
        int nbE, int nbC) {
    int bid = blockIdx.x, tid = threadIdx.x;
    if (bid < nbE) {
        int e = bid * 256 + tid;
        if (e < nE) rank[e] = atomicAdd(&deg[dst[e]], 1);
    } else if (bid < nbE + nbC) {
        int i = (bid - nbE) * 256 + tid;
        if (i < n4) {
            float4 v = ((const float4*)x)[i];
            ushort4 o;
            o.x = f2bf(v.x); o.y = f2bf(v.y); o.z = f2bf(v.z); o.w = f2bf(v.w);
            ((ushort4*)xb)[i] = o;
        }
    } else {
        int pb = bid - nbE - nbC;                 // 0..31
        const float* wl = (pb < 16) ? w1l : w2l;
        const float* wr = (pb < 16) ? w1r : w2r;
        unsigned short* wp = (pb < 16) ? wp1 : wp2;
        int t = (pb & 15) * 256 + tid;            // 0..4095
        int lane = t & 63, s = (t >> 6) & 7, nt = t >> 9;
        int kbase = s * 32 + ((lane >> 4) * 8);
        int c = nt * 16 + (lane & 15);
        unsigned short tmp[8];
        #pragma unroll
        for (int j = 0; j < 8; ++j) {
            int k = kbase + j;
            float w = (k < 128) ? wl[k * 128 + c] : wr[(k - 128) * 128 + c];
            tmp[j] = f2bf(w);
        }
        ushort4 lo, hi;
        lo.x = tmp[0]; lo.y = tmp[1]; lo.z = tmp[2]; lo.w = tmp[3];
        hi.x = tmp[4]; hi.y = tmp[5]; hi.z = tmp[6]; hi.w = tmp[7];
        ((ushort4*)wp)[t * 2 + 0] = lo;
        ((ushort4*)wp)[t * 2 + 1] = hi;
    }
}

__global__ __launch_bounds__(256) void scan1_k(const int* __restrict__ deg,
                                               int* __restrict__ rowstart,
                                               int* __restrict__ bsum, int n) {
    __shared__ int s[256];
    int tid = threadIdx.x;
    int i = blockIdx.x * 256 + tid;
    int v = (i < n) ? deg[i] : 0;
    s[tid] = v;
    __syncthreads();
    for (int off = 1; off < 256; off <<= 1) {
        int t = (tid >= off) ? s[tid - off] : 0;
        __syncthreads();
        s[tid] += t;
        __syncthreads();
    }
    if (i < n) rowstart[i] = s[tid] - v;
    if (tid == 255) bsum[blockIdx.x] = s[255];
}

__global__ __launch_bounds__(256) void scan2_k(int* __restrict__ bsum, int nb) {
    __shared__ int s[256];
    int tid = threadIdx.x;
    int v = (tid < nb) ? bsum[tid] : 0;
    s[tid] = v;
    __syncthreads();
    for (int off = 1; off < 256; off <<= 1) {
        int t = (tid >= off) ? s[tid - off] : 0;
        __syncthreads();
        s[tid] += t;
        __syncthreads();
    }
    if (tid < nb) bsum[tid] = s[tid] - v;
}

__global__ void addoff_k(int* __restrict__ rowstart, const int* __restrict__ bsum, int n) {
    int i = blockIdx.x * blockDim.x + threadIdx.x;
    if (i < n) rowstart[i] += bsum[blockIdx.x];
}

// --- atomic-free CSR fill, class-partitioned by node range -----------------
__global__ __launch_bounds__(256) void fill_swz_k(
        const int* __restrict__ src, const int* __restrict__ dst,
        const int* __restrict__ rowstart, const int* __restrict__ rank,
        int* __restrict__ csr, int nE, int rngSize) {
    int cls = blockIdx.x & 7;
    int lo = cls * rngSize, hi = lo + rngSize;
    int nb = gridDim.x >> 3;
    int bi = blockIdx.x >> 3;
    for (int e = bi * 256 + threadIdx.x; e < nE; e += nb * 256) {
        int d = dst[e];
        if (d >= lo && d < hi)
            csr[rowstart[d] + rank[e]] = src[e];
    }
}

// --- fused SAGE layer: gather-mean -> LDS -> MFMA -> relu -> store ----------
// 256 thr = 4 waves. Wave w owns output rows blockIdx*64 + w*16 .. +15.
// Phase 1: wave gathers its 16 nodes (2 interleaved streams -> 16 uint2
//          loads in flight), writes bf16 means to its private LDS tile.
//          Rows padded to 136 ushorts (272B) -> bank-balanced b128 reads.
// Phase 2: MFMA 16 rows x 128 cols, A-lo from LDS, A-hi (root) from global,
//          B from packed weight stream. No __syncthreads needed: each wave
//          reads only LDS it wrote itself.
__global__ __launch_bounds__(256) void sage_layer_k(
        const uint2* __restrict__ feat,           // gather src [n][32] uint2
        const unsigned short* __restrict__ root,  // [n][128] bf16
        const int* __restrict__ csr, const int* __restrict__ rowstart,
        const int* __restrict__ deg,
        const unsigned short* __restrict__ wp,    // packed weights
        const float* __restrict__ bias,           // [128] f32
        unsigned short* __restrict__ outp,        // [n][128] bf16
        int n) {
    __shared__ __align__(16) unsigned short arow[4][16][136];
    int tid = threadIdx.x;
    int wave = tid >> 6, lane = tid & 63;
    int rowTile = blockIdx.x * 64 + wave * 16;
    int h = lane >> 5, hl = lane & 31;

    // ---- phase 1: gather 16 nodes, 2 at a time ----
    for (int r = 0; r < 16; r += 2) {
        int nA = rowTile + r, nB = rowTile + r + 1;
        int sA = 0, dA = 0, sB = 0, dB = 0;
        if (nA < n) { sA = rowstart[nA]; dA = deg[nA]; }
        if (nB < n) { sB = rowstart[nB]; dB = deg[nB]; }
        float a0 = 0.f, a1 = 0.f, a2 = 0.f, a3 = 0.f;
        float b0 = 0.f, b1 = 0.f, b2 = 0.f, b3 = 0.f;
        int dmax = max(dA, dB);
        for (int be = 0; be < dmax; be += 16) {
            uint2 wA[8], wB[8];
            #pragma unroll
            for (int k = 0; k < 8; ++k) {
                int e = be + 2 * k + h;
                int iA = (e < dA) ? csr[sA + e] : -1;
                int iB = (e < dB) ? csr[sB + e] : -1;
                wA[k] = feat[(size_t)max(iA, 0) * 32 + hl];
                wB[k] = feat[(size_t)max(iB, 0) * 32 + hl];
                if (iA < 0) { wA[k].x = 0; wA[k].y = 0; }
                if (iB < 0) { wB[k].x = 0; wB[k].y = 0; }
            }
            #pragma unroll
            for (int k = 0; k < 8; ++k) {
                a0 += bf2f((unsigned short)(wA[k].x & 0xffff));
                a1 += bf2f((unsigned short)(wA[k].x >> 16));
                a2 += bf2f((unsigned short)(wA[k].y & 0xffff));
                a3 += bf2f((unsigned short)(wA[k].y >> 16));
                b0 += bf2f((unsigned short)(wB[k].x & 0xffff));
                b1 += bf2f((unsigned short)(wB[k].x >> 16));
                b2 += bf2f((unsigned short)(wB[k].y & 0xffff));
                b3 += bf2f((unsigned short)(wB[k].y >> 16));
            }
        }
        a0 += __shfl_xor(a0, 32, 64);
        a1 += __shfl_xor(a1, 32, 64);
        a2 += __shfl_xor(a2, 32, 64);
        a3 += __shfl_xor(a3, 32, 64);
        b0 += __shfl_xor(b0, 32, 64);
        b1 += __shfl_xor(b1, 32, 64);
        b2 += __shfl_xor(b2, 32, 64);
        b3 += __shfl_xor(b3, 32, 64);
        if (h == 0) {
            float invA = (dA > 0) ? 1.0f / (float)dA : 0.0f;
            float invB = (dB > 0) ? 1.0f / (float)dB : 0.0f;
            uint2 oA, oB;
            oA.x = ((unsigned)f2bf(a1 * invA) << 16) | (unsigned)f2bf(a0 * invA);
            oA.y = ((unsigned)f2bf(a3 * invA) << 16) | (unsigned)f2bf(a2 * invA);
            oB.x = ((unsigned)f2bf(b1 * invB) << 16) | (unsigned)f2bf(b0 * invB);
            oB.y = ((unsigned)f2bf(b3 * invB) << 16) | (unsigned)f2bf(b2 * invB);
            *(uint2*)&arow[wave][r][hl * 4] = oA;
            *(uint2*)&arow[wave][r + 1][hl * 4] = oB;
        }
    }

    // ---- phase 2: MFMA (same wave reads its own LDS rows; no barrier) ----
    int lrow = lane & 15, lk = lane >> 4;
    bf16x8 a[8];
    #pragma unroll
    for (int s = 0; s < 4; ++s)
        a[s] = *(const bf16x8*)&arow[wave][lrow][s * 32 + lk * 8];
    int grow = rowTile + lrow;
    if (grow >= n) grow = n - 1;
    const unsigned short* rbase = root + (size_t)grow * FDIM + lk * 8;
    #pragma unroll
    for (int s = 0; s < 4; ++s)
        a[4 + s] = *(const bf16x8*)(rbase + s * 32);

    const bf16x8* bp = (const bf16x8*)wp;
    int ocol = lane & 15;
    int orow0 = rowTile + (lane >> 4) * 4;

    #pragma unroll
    for (int nt = 0; nt < 8; ++nt) {
        float bv = bias[nt * 16 + ocol];
        f32x4 acc = {bv, bv, bv, bv};
        #pragma unroll
        for (int s = 0; s < 8; ++s) {
            bf16x8 b = bp[(nt * 8 + s) * 64 + lane];
            acc = __builtin_amdgcn_mfma_f32_16x16x32_bf16(a[s], b, acc, 0, 0, 0);
        }
        #pragma unroll
        for (int r = 0; r < 4; ++r) {
            int orow = orow0 + r;
            if (orow < n) {
                float v = fmaxf(acc[r], 0.0f);
                outp[(size_t)orow * FDIM + nt * 16 + ocol] = f2bf(v);
            }
        }
    }
}

// --- segmented global mean pool: 64 nodes/block, batch sorted --------------
__global__ __launch_bounds__(256) void pool_seg_k(
        const unsigned short* __restrict__ h,     // [nN][128] bf16
        const int* __restrict__ batch,
        float* __restrict__ gsum, int* __restrict__ gcnt, int nN) {
    __shared__ int bw[64];
    __shared__ float red[8][32][4];
    int base = blockIdx.x * 64;
    if (base >= nN) return;
    int tid = threadIdx.x;
    int rg = tid >> 5, cs = tid & 31;
    int cnt = min(64, nN - base);
    if (tid < 64) bw[tid] = batch[min(base + tid, nN - 1)];
    __syncthreads();
    int g0 = bw[0], g1 = bw[cnt - 1];

    for (int g = g0; g <= g1; ++g) {
        int s = 0;
        while (s < cnt && bw[s] < g) ++s;
        int e = s;
        while (e < cnt && bw[e] == g) ++e;

        float a0 = 0.f, a1 = 0.f, a2 = 0.f, a3 = 0.f;
        for (int i = s + rg; i < e; i += 8) {
            uint2 v = ((const uint2*)(h + (size_t)(base + i) * FDIM))[cs];
            a0 += bf2f((unsigned short)(v.x & 0xffff));
            a1 += bf2f((unsigned short)(v.x >> 16));
            a2 += bf2f((unsigned short)(v.y & 0xffff));
            a3 += bf2f((unsigned short)(v.y >> 16));
        }
        red[rg][cs][0] = a0; red[rg][cs][1] = a1;
        red[rg][cs][2] = a2; red[rg][cs][3] = a3;
        __syncthreads();
        if (rg == 0 && e > s) {
            #pragma unroll
            for (int r = 1; r < 8; ++r) {
                a0 += red[r][cs][0]; a1 += red[r][cs][1];
                a2 += red[r][cs][2]; a3 += red[r][cs][3];
            }
            float* go = gsum + (size_t)g * FDIM + cs * 4;
            atomicAdd(go + 0, a0);
            atomicAdd(go + 1, a1);
            atomicAdd(go + 2, a2);
            atomicAdd(go + 3, a3);
            if (cs == 0) atomicAdd(&gcnt[g], e - s);
        }
        __syncthreads();
    }
}

// --- head: logits = mean @ wf + bf ; log_softmax ---------------------------
__global__ __launch_bounds__(128) void head_k(const float* __restrict__ gsum,
                                              const int* __restrict__ gcnt,
                                              const float* __restrict__ wf,
                                              const float* __restrict__ bf,
                                              float* __restrict__ out, int nG) {
    int g = blockIdx.x;
    if (g >= nG) return;
    __shared__ float row[FDIM];
    int tid = threadIdx.x;
    float inv = 1.0f / fmaxf((float)gcnt[g], 1.0f);
    row[tid] = gsum[(size_t)g * FDIM + tid] * inv;
    __syncthreads();

    float logit = -1e30f;
    if (tid < 16) {
        logit = bf[tid];
        for (int k = 0; k < FDIM; ++k) logit += row[k] * wf[k * 16 + tid];
    }
    float m = logit;
    for (int off = 8; off >= 1; off >>= 1) m = fmaxf(m, __shfl_xor(m, off, 64));
    float ev = (tid < 16) ? expf(logit - m) : 0.0f;
    float sum = ev;
    for (int off = 8; off >= 1; off >>= 1) sum += __shfl_xor(sum, off, 64);
    if (tid < 16) out[(size_t)g * 16 + tid] = logit - m - logf(sum);
}

extern "C" void kernel_launch(void* const* d_in, const int* in_sizes, int n_in,
                              void* d_out, int out_size, void* d_ws, size_t ws_size,
                              hipStream_t stream) {
    const float* x    = (const float*)d_in[0];
    const int*   ei   = (const int*)d_in[1];
    const int*   batch= (const int*)d_in[2];
    const float* w1l  = (const float*)d_in[3];
    const float* b1   = (const float*)d_in[4];
    const float* w1r  = (const float*)d_in[5];
    const float* w2l  = (const float*)d_in[6];
    const float* b2   = (const float*)d_in[7];
    const float* w2r  = (const float*)d_in[8];
    const float* wf   = (const float*)d_in[9];
    const float* bf   = (const float*)d_in[10];
    float* out = (float*)d_out;

    const int N = in_sizes[0] / FDIM;
    const int E = in_sizes[1] / 2;
    const int G = out_size / 16;
    const int* src = ei;
    const int* dst = ei + E;
    const int NB = (N + 255) / 256;              // <= 256 for scan2_k

    // --- workspace layout ---
    char* ws = (char*)d_ws;
    size_t off = 0;
    auto alloc = [&](size_t bytes) { void* p = ws + off; off = (off + bytes + 255) & ~(size_t)255; return p; };
    unsigned short* xb   = (unsigned short*)alloc((size_t)N * FDIM * 2); // also h2
    unsigned short* h1   = (unsigned short*)alloc((size_t)N * FDIM * 2);
    unsigned short* wp1  = (unsigned short*)alloc(8 * 8 * 64 * 8 * 2);
    unsigned short* wp2  = (unsigned short*)alloc(8 * 8 * 64 * 8 * 2);
    int* deg      = (int*)alloc((size_t)N * sizeof(int));
    int* rowstart = (int*)alloc((size_t)N * sizeof(int));
    int* bsum     = (int*)alloc(256 * sizeof(int));
    int* csr      = (int*)alloc((size_t)E * sizeof(int));
    int* rank     = (int*)alloc((size_t)E * sizeof(int));
    float* gsum   = (float*)alloc((size_t)G * FDIM * sizeof(float));
    int*   gcnt   = (int*)alloc((size_t)G * sizeof(int));
    unsigned short* h2 = xb;                      // xb dead once h2 is written

    // --- zero accumulators ---
    hipMemsetAsync(deg, 0, (size_t)N * sizeof(int), stream);
    hipMemsetAsync(gsum, 0, (size_t)G * FDIM * sizeof(float), stream);
    hipMemsetAsync(gcnt, 0, (size_t)G * sizeof(int), stream);

    // --- merged prep: deg/rank | cvt | packs ---
    const int nbE = (E + 255) / 256;
    const int nbC = (N * FDIM / 4 + 255) / 256;
    prep_k<<<nbE + nbC + 32, 256, 0, stream>>>(dst, deg, rank, E,
                                               x, xb, N * FDIM / 4,
                                               w1l, w1r, wp1, w2l, w2r, wp2,
                                               nbE, nbC);

    // --- CSR offsets + localized fill ---
    scan1_k<<<NB, 256, 0, stream>>>(deg, rowstart, bsum, N);
    scan2_k<<<1, 256, 0, stream>>>(bsum, NB);
    addoff_k<<<NB, 256, 0, stream>>>(rowstart, bsum, N);
    {
        int rngSize = (N + 7) / 8;
        fill_swz_k<<<2048, 256, 0, stream>>>(src, dst, rowstart, rank, csr, E, rngSize);
    }

    // --- fused layers ---
    sage_layer_k<<<(N + 63) / 64, 256, 0, stream>>>((const uint2*)xb, xb, csr, rowstart,
                                                    deg, wp1, b1, h1, N);
    sage_layer_k<<<(N + 63) / 64, 256, 0, stream>>>((const uint2*)h1, h1, csr, rowstart,
                                                    deg, wp2, b2, h2, N);

    // --- pool + head ---
    pool_seg_k<<<(N + 63) / 64, 256, 0, stream>>>(h2, batch, gsum, gcnt, N);
    head_k<<<G, 128, 0, stream>>>(gsum, gcnt, wf, bf, out, G);
}

// Round 8
// 218.936 us; speedup vs baseline: 1.0598x; 1.0598x over previous
//
#include <hip/hip_runtime.h>
#include <hip/hip_bf16.h>
#include <math.h>

// ---------------------------------------------------------------------------
// GraphSAGE inference, bf16 MFMA pipeline.
//   h1 = relu([aggr(x)|x] @ [w1l;w1r] + b1)      (MFMA, K=256)
//   h2 = relu([aggr(h1)|h1] @ [w2l;w2r] + b2)
//   out = log_softmax(mean_pool(h2) @ wf + bf)
// R1: atomics -> CSR+gather. R2: bf16 MFMA GEMM, packed weights.
// R3: gather MLP. R4: atomic-free localized CSR fill. R5: segmented pool.
// R6: fused layer REGRESSED (occupancy collapse) -> reverted.
// R7: column-class partitioned gather: each XCD's L2 caches one 3.2MB
//     64B-column slice of the feature table (class = (blockIdx&7)&3).
// ---------------------------------------------------------------------------

#define FDIM 128

typedef __attribute__((ext_vector_type(8))) short bf16x8;
typedef __attribute__((ext_vector_type(4))) float f32x4;

__device__ inline unsigned short f2bf(float f) {
    union { float f; unsigned u; } v; v.f = f;
    unsigned r = v.u + 0x7fff + ((v.u >> 16) & 1);   // RNE
    return (unsigned short)(r >> 16);
}
__device__ inline float bf2f(unsigned short b) {
    union { unsigned u; float f; } v; v.u = ((unsigned)b) << 16;
    return v.f;
}

// --- merged prep: deg+rank | f32->bf16 cvt | weight packs -------------------
__global__ __launch_bounds__(256) void prep_k(
        const int* __restrict__ dst, int* __restrict__ deg, int* __restrict__ rank, int nE,
        const float* __restrict__ x, unsigned short* __restrict__ xb, int n4,
        const float* __restrict__ w1l, const float* __restrict__ w1r,
        unsigned short* __restrict__ wp1,
        const float* __restrict__ w2l, const float* __restrict__ w2r,
        unsigned short* __restrict__ wp2,
        int nbE, int nbC) {
    int bid = blockIdx.x, tid = threadIdx.x;
    if (bid < nbE) {
        int e = bid * 256 + tid;
        if (e < nE) rank[e] = atomicAdd(&deg[dst[e]], 1);
    } else if (bid < nbE + nbC) {
        int i = (bid - nbE) * 256 + tid;
        if (i < n4) {
            float4 v = ((const float4*)x)[i];
            ushort4 o;
            o.x = f2bf(v.x); o.y = f2bf(v.y); o.z = f2bf(v.z); o.w = f2bf(v.w);
            ((ushort4*)xb)[i] = o;
        }
    } else {
        int pb = bid - nbE - nbC;                 // 0..31
        const float* wl = (pb < 16) ? w1l : w2l;
        const float* wr = (pb < 16) ? w1r : w2r;
        unsigned short* wp = (pb < 16) ? wp1 : wp2;
        int t = (pb & 15) * 256 + tid;            // 0..4095
        int lane = t & 63, s = (t >> 6) & 7, nt = t >> 9;
        int kbase = s * 32 + ((lane >> 4) * 8);
        int c = nt * 16 + (lane & 15);
        unsigned short tmp[8];
        #pragma unroll
        for (int j = 0; j < 8; ++j) {
            int k = kbase + j;
            float w = (k < 128) ? wl[k * 128 + c] : wr[(k - 128) * 128 + c];
            tmp[j] = f2bf(w);
        }
        ushort4 lo, hi;
        lo.x = tmp[0]; lo.y = tmp[1]; lo.z = tmp[2]; lo.w = tmp[3];
        hi.x = tmp[4]; hi.y = tmp[5]; hi.z = tmp[6]; hi.w = tmp[7];
        ((ushort4*)wp)[t * 2 + 0] = lo;
        ((ushort4*)wp)[t * 2 + 1] = hi;
    }
}

__global__ __launch_bounds__(256) void scan1_k(const int* __restrict__ deg,
                                               int* __restrict__ rowstart,
                                               int* __restrict__ bsum, int n) {
    __shared__ int s[256];
    int tid = threadIdx.x;
    int i = blockIdx.x * 256 + tid;
    int v = (i < n) ? deg[i] : 0;
    s[tid] = v;
    __syncthreads();
    for (int off = 1; off < 256; off <<= 1) {
        int t = (tid >= off) ? s[tid - off] : 0;
        __syncthreads();
        s[tid] += t;
        __syncthreads();
    }
    if (i < n) rowstart[i] = s[tid] - v;
    if (tid == 255) bsum[blockIdx.x] = s[255];
}

__global__ __launch_bounds__(256) void scan2_k(int* __restrict__ bsum, int nb) {
    __shared__ int s[256];
    int tid = threadIdx.x;
    int v = (tid < nb) ? bsum[tid] : 0;
    s[tid] = v;
    __syncthreads();
    for (int off = 1; off < 256; off <<= 1) {
        int t = (tid >= off) ? s[tid - off] : 0;
        __syncthreads();
        s[tid] += t;
        __syncthreads();
    }
    if (tid < nb) bsum[tid] = s[tid] - v;
}

__global__ void addoff_k(int* __restrict__ rowstart, const int* __restrict__ bsum, int n) {
    int i = blockIdx.x * blockDim.x + threadIdx.x;
    if (i < n) rowstart[i] += bsum[blockIdx.x];
}

// --- atomic-free CSR fill, class-partitioned by node range -----------------
__global__ __launch_bounds__(256) void fill_swz_k(
        const int* __restrict__ src, const int* __restrict__ dst,
        const int* __restrict__ rowstart, const int* __restrict__ rank,
        int* __restrict__ csr, int nE, int rngSize) {
    int cls = blockIdx.x & 7;
    int lo = cls * rngSize, hi = lo + rngSize;
    int nb = gridDim.x >> 3;
    int bi = blockIdx.x >> 3;
    for (int e = bi * 256 + threadIdx.x; e < nE; e += nb * 256) {
        int d = dst[e];
        if (d >= lo && d < hi)
            csr[rowstart[d] + rank[e]] = src[e];
    }
}

// --- column-class gather-mean ----------------------------------------------
// Feature row = 256B = 4 classes x 64B (one cache line each). Block's class
// = (blockIdx&7)&3 -> under round-robin block->XCD dispatch each XCD only
// touches one 3.2MB slice (fits its 4MB L2). Correct for ANY mapping:
// (node-group, class) pairs partition the work exactly once.
// Wave: 2 nodes, lanes = 8 edge-slots x 8 col-slots, 16 edges/iter.
__global__ __launch_bounds__(256) void gather_cls_k(
        const uint2* __restrict__ feat,           // [n][32] uint2 (256B rows)
        const int* __restrict__ csr, const int* __restrict__ rowstart,
        const int* __restrict__ deg, uint2* __restrict__ outr,
        int n, int perHalf) {
    int b = blockIdx.x;
    int xcd = b & 7;
    int cls = xcd & 3;
    int grp = (b >> 3) + ((xcd >> 2) ? perHalf : 0);
    int wave = threadIdx.x >> 6, lane = threadIdx.x & 63;
    int es = lane >> 3, cs = lane & 7;            // edge slot, col slot
    int colOff = cls * 8 + cs;                    // uint2 index within row

    int nodeA = grp * 8 + wave * 2;
    int nodeB = nodeA + 1;
    int sA = 0, dA = 0, sB = 0, dB = 0;
    if (nodeA < n) { sA = rowstart[nodeA]; dA = deg[nodeA]; }
    if (nodeB < n) { sB = rowstart[nodeB]; dB = deg[nodeB]; }

    float a0 = 0.f, a1 = 0.f, a2 = 0.f, a3 = 0.f;
    float b0 = 0.f, b1 = 0.f, b2 = 0.f, b3 = 0.f;
    int dmax = max(dA, dB);
    for (int base = 0; base < dmax; base += 16) {
        int e0 = base + es, e1 = base + 8 + es;
        int iA0 = (e0 < dA) ? csr[sA + e0] : -1;
        int iA1 = (e1 < dA) ? csr[sA + e1] : -1;
        int iB0 = (e0 < dB) ? csr[sB + e0] : -1;
        int iB1 = (e1 < dB) ? csr[sB + e1] : -1;
        uint2 wA0 = feat[(size_t)max(iA0, 0) * 32 + colOff];
        uint2 wA1 = feat[(size_t)max(iA1, 0) * 32 + colOff];
        uint2 wB0 = feat[(size_t)max(iB0, 0) * 32 + colOff];
        uint2 wB1 = feat[(size_t)max(iB1, 0) * 32 + colOff];
        if (iA0 < 0) { wA0.x = 0; wA0.y = 0; }
        if (iA1 < 0) { wA1.x = 0; wA1.y = 0; }
        if (iB0 < 0) { wB0.x = 0; wB0.y = 0; }
        if (iB1 < 0) { wB1.x = 0; wB1.y = 0; }
        a0 += bf2f((unsigned short)(wA0.x & 0xffff)) + bf2f((unsigned short)(wA1.x & 0xffff));
        a1 += bf2f((unsigned short)(wA0.x >> 16))    + bf2f((unsigned short)(wA1.x >> 16));
        a2 += bf2f((unsigned short)(wA0.y & 0xffff)) + bf2f((unsigned short)(wA1.y & 0xffff));
        a3 += bf2f((unsigned short)(wA0.y >> 16))    + bf2f((unsigned short)(wA1.y >> 16));
        b0 += bf2f((unsigned short)(wB0.x & 0xffff)) + bf2f((unsigned short)(wB1.x & 0xffff));
        b1 += bf2f((unsigned short)(wB0.x >> 16))    + bf2f((unsigned short)(wB1.x >> 16));
        b2 += bf2f((unsigned short)(wB0.y & 0xffff)) + bf2f((unsigned short)(wB1.y & 0xffff));
        b3 += bf2f((unsigned short)(wB0.y >> 16))    + bf2f((unsigned short)(wB1.y >> 16));
    }
    // reduce across the 8 edge slots (lane bits 3..5)
    #pragma unroll
    for (int m = 8; m <= 32; m <<= 1) {
        a0 += __shfl_xor(a0, m, 64); a1 += __shfl_xor(a1, m, 64);
        a2 += __shfl_xor(a2, m, 64); a3 += __shfl_xor(a3, m, 64);
        b0 += __shfl_xor(b0, m, 64); b1 += __shfl_xor(b1, m, 64);
        b2 += __shfl_xor(b2, m, 64); b3 += __shfl_xor(b3, m, 64);
    }

    if (es == 0) {
        if (nodeA < n) {
            float inv = (dA > 0) ? 1.0f / (float)dA : 0.0f;
            uint2 o;
            o.x = ((unsigned)f2bf(a1 * inv) << 16) | (unsigned)f2bf(a0 * inv);
            o.y = ((unsigned)f2bf(a3 * inv) << 16) | (unsigned)f2bf(a2 * inv);
            outr[(size_t)nodeA * 32 + colOff] = o;
        }
        if (nodeB < n) {
            float inv = (dB > 0) ? 1.0f / (float)dB : 0.0f;
            uint2 o;
            o.x = ((unsigned)f2bf(b1 * inv) << 16) | (unsigned)f2bf(b0 * inv);
            o.y = ((unsigned)f2bf(b3 * inv) << 16) | (unsigned)f2bf(b2 * inv);
            outr[(size_t)nodeB * 32 + colOff] = o;
        }
    }
}

// --- fused SAGE GEMM: out = relu([A|R] @ Wpack + bias), bf16 MFMA ----------
__global__ __launch_bounds__(256) void gemm_mfma_k(
        const unsigned short* __restrict__ A,     // aggr [n][128] bf16
        const unsigned short* __restrict__ R,     // root [n][128] bf16
        const unsigned short* __restrict__ wp,    // packed weights
        const float* __restrict__ bias,           // [128] f32
        unsigned short* __restrict__ outp,        // [n][128] bf16
        int n) {
    int tid = threadIdx.x;
    int wave = tid >> 6, lane = tid & 63;
    int rowTile = blockIdx.x * 64 + wave * 16;
    int lrow = lane & 15, lk = lane >> 4;

    int arow = rowTile + lrow;
    if (arow >= n) arow = n - 1;                  // clamp; stores are guarded

    bf16x8 a[8];
    const unsigned short* abase = A + (size_t)arow * FDIM + lk * 8;
    const unsigned short* rbase = R + (size_t)arow * FDIM + lk * 8;
    #pragma unroll
    for (int s = 0; s < 4; ++s) a[s] = *(const bf16x8*)(abase + s * 32);
    #pragma unroll
    for (int s = 0; s < 4; ++s) a[4 + s] = *(const bf16x8*)(rbase + s * 32);

    const bf16x8* bp = (const bf16x8*)wp;
    int ocol = lane & 15;
    int orow0 = rowTile + (lane >> 4) * 4;

    #pragma unroll
    for (int nt = 0; nt < 8; ++nt) {
        float bv = bias[nt * 16 + ocol];
        f32x4 acc = {bv, bv, bv, bv};
        #pragma unroll
        for (int s = 0; s < 8; ++s) {
            bf16x8 b = bp[(nt * 8 + s) * 64 + lane];
            acc = __builtin_amdgcn_mfma_f32_16x16x32_bf16(a[s], b, acc, 0, 0, 0);
        }
        #pragma unroll
        for (int r = 0; r < 4; ++r) {
            int orow = orow0 + r;
            if (orow < n) {
                float v = fmaxf(acc[r], 0.0f);
                outp[(size_t)orow * FDIM + nt * 16 + ocol] = f2bf(v);
            }
        }
    }
}

// --- segmented global mean pool: 64 nodes/block, batch sorted --------------
__global__ __launch_bounds__(256) void pool_seg_k(
        const unsigned short* __restrict__ h,     // [nN][128] bf16
        const int* __restrict__ batch,
        float* __restrict__ gsum, int* __restrict__ gcnt, int nN) {
    __shared__ int bw[64];
    __shared__ float red[8][32][4];
    int base = blockIdx.x * 64;
    if (base >= nN) return;
    int tid = threadIdx.x;
    int rg = tid >> 5, cs = tid & 31;
    int cnt = min(64, nN - base);
    if (tid < 64) bw[tid] = batch[min(base + tid, nN - 1)];
    __syncthreads();
    int g0 = bw[0], g1 = bw[cnt - 1];

    for (int g = g0; g <= g1; ++g) {
        int s = 0;
        while (s < cnt && bw[s] < g) ++s;
        int e = s;
        while (e < cnt && bw[e] == g) ++e;

        float a0 = 0.f, a1 = 0.f, a2 = 0.f, a3 = 0.f;
        for (int i = s + rg; i < e; i += 8) {
            uint2 v = ((const uint2*)(h + (size_t)(base + i) * FDIM))[cs];
            a0 += bf2f((unsigned short)(v.x & 0xffff));
            a1 += bf2f((unsigned short)(v.x >> 16));
            a2 += bf2f((unsigned short)(v.y & 0xffff));
            a3 += bf2f((unsigned short)(v.y >> 16));
        }
        red[rg][cs][0] = a0; red[rg][cs][1] = a1;
        red[rg][cs][2] = a2; red[rg][cs][3] = a3;
        __syncthreads();
        if (rg == 0 && e > s) {
            #pragma unroll
            for (int r = 1; r < 8; ++r) {
                a0 += red[r][cs][0]; a1 += red[r][cs][1];
                a2 += red[r][cs][2]; a3 += red[r][cs][3];
            }
            float* go = gsum + (size_t)g * FDIM + cs * 4;
            atomicAdd(go + 0, a0);
            atomicAdd(go + 1, a1);
            atomicAdd(go + 2, a2);
            atomicAdd(go + 3, a3);
            if (cs == 0) atomicAdd(&gcnt[g], e - s);
        }
        __syncthreads();
    }
}

// --- head: logits = mean @ wf + bf ; log_softmax ---------------------------
__global__ __launch_bounds__(128) void head_k(const float* __restrict__ gsum,
                                              const int* __restrict__ gcnt,
                                              const float* __restrict__ wf,
                                              const float* __restrict__ bf,
                                              float* __restrict__ out, int nG) {
    int g = blockIdx.x;
    if (g >= nG) return;
    __shared__ float row[FDIM];
    int tid = threadIdx.x;
    float inv = 1.0f / fmaxf((float)gcnt[g], 1.0f);
    row[tid] = gsum[(size_t)g * FDIM + tid] * inv;
    __syncthreads();

    float logit = -1e30f;
    if (tid < 16) {
        logit = bf[tid];
        for (int k = 0; k < FDIM; ++k) logit += row[k] * wf[k * 16 + tid];
    }
    float m = logit;
    for (int off = 8; off >= 1; off >>= 1) m = fmaxf(m, __shfl_xor(m, off, 64));
    float ev = (tid < 16) ? expf(logit - m) : 0.0f;
    float sum = ev;
    for (int off = 8; off >= 1; off >>= 1) sum += __shfl_xor(sum, off, 64);
    if (tid < 16) out[(size_t)g * 16 + tid] = logit - m - logf(sum);
}

extern "C" void kernel_launch(void* const* d_in, const int* in_sizes, int n_in,
                              void* d_out, int out_size, void* d_ws, size_t ws_size,
                              hipStream_t stream) {
    const float* x    = (const float*)d_in[0];
    const int*   ei   = (const int*)d_in[1];
    const int*   batch= (const int*)d_in[2];
    const float* w1l  = (const float*)d_in[3];
    const float* b1   = (const float*)d_in[4];
    const float* w1r  = (const float*)d_in[5];
    const float* w2l  = (const float*)d_in[6];
    const float* b2   = (const float*)d_in[7];
    const float* w2r  = (const float*)d_in[8];
    const float* wf   = (const float*)d_in[9];
    const float* bf   = (const float*)d_in[10];
    float* out = (float*)d_out;

    const int N = in_sizes[0] / FDIM;
    const int E = in_sizes[1] / 2;
    const int G = out_size / 16;
    const int* src = ei;
    const int* dst = ei + E;
    const int NB = (N + 255) / 256;              // <= 256 for scan2_k

    // --- workspace layout ---
    char* ws = (char*)d_ws;
    size_t off = 0;
    auto alloc = [&](size_t bytes) { void* p = ws + off; off = (off + bytes + 255) & ~(size_t)255; return p; };
    unsigned short* xb   = (unsigned short*)alloc((size_t)N * FDIM * 2); // also h2
    unsigned short* aggr = (unsigned short*)alloc((size_t)N * FDIM * 2);
    unsigned short* h1   = (unsigned short*)alloc((size_t)N * FDIM * 2);
    unsigned short* wp1  = (unsigned short*)alloc(8 * 8 * 64 * 8 * 2);
    unsigned short* wp2  = (unsigned short*)alloc(8 * 8 * 64 * 8 * 2);
    int* deg      = (int*)alloc((size_t)N * sizeof(int));
    int* rowstart = (int*)alloc((size_t)N * sizeof(int));
    int* bsum     = (int*)alloc(256 * sizeof(int));
    int* csr      = (int*)alloc((size_t)E * sizeof(int));
    int* rank     = (int*)alloc((size_t)E * sizeof(int));
    float* gsum   = (float*)alloc((size_t)G * FDIM * sizeof(float));
    int*   gcnt   = (int*)alloc((size_t)G * sizeof(int));
    unsigned short* h2 = xb;                      // xb dead once h2 is written

    // --- zero accumulators ---
    hipMemsetAsync(deg, 0, (size_t)N * sizeof(int), stream);
    hipMemsetAsync(gsum, 0, (size_t)G * FDIM * sizeof(float), stream);
    hipMemsetAsync(gcnt, 0, (size_t)G * sizeof(int), stream);

    // --- merged prep: deg/rank | cvt | packs ---
    const int nbE = (E + 255) / 256;
    const int nbC = (N * FDIM / 4 + 255) / 256;
    prep_k<<<nbE + nbC + 32, 256, 0, stream>>>(dst, deg, rank, E,
                                               x, xb, N * FDIM / 4,
                                               w1l, w1r, wp1, w2l, w2r, wp2,
                                               nbE, nbC);

    // --- CSR offsets + localized fill ---
    scan1_k<<<NB, 256, 0, stream>>>(deg, rowstart, bsum, N);
    scan2_k<<<1, 256, 0, stream>>>(bsum, NB);
    addoff_k<<<NB, 256, 0, stream>>>(rowstart, bsum, N);
    {
        int rngSize = (N + 7) / 8;
        fill_swz_k<<<2048, 256, 0, stream>>>(src, dst, rowstart, rank, csr, E, rngSize);
    }

    // --- gather grid: 8 * perHalf blocks; class = (blockIdx&7)&3 ---
    const int nGrpTot = (N + 7) / 8;
    const int perHalf = (nGrpTot + 1) / 2;
    const int gatherGrid = 8 * perHalf;

    // --- layer 1 ---
    gather_cls_k<<<gatherGrid, 256, 0, stream>>>((const uint2*)xb, csr, rowstart, deg,
                                                 (uint2*)aggr, N, perHalf);
    gemm_mfma_k<<<(N + 63) / 64, 256, 0, stream>>>(aggr, xb, wp1, b1, h1, N);

    // --- layer 2 ---
    gather_cls_k<<<gatherGrid, 256, 0, stream>>>((const uint2*)h1, csr, rowstart, deg,
                                                 (uint2*)aggr, N, perHalf);
    gemm_mfma_k<<<(N + 63) / 64, 256, 0, stream>>>(aggr, h1, wp2, b2, h2, N);

    // --- pool + head ---
    pool_seg_k<<<(N + 63) / 64, 256, 0, stream>>>(h2, batch, gsum, gcnt, N);
    head_k<<<G, 128, 0, stream>>>(gsum, gcnt, wf, bf, out, G);
}

// Round 9
// 177.128 us; speedup vs baseline: 1.3099x; 1.2360x over previous
//
#include <hip/hip_runtime.h>
#include <hip/hip_bf16.h>
#include <math.h>

// ---------------------------------------------------------------------------
// GraphSAGE inference, bf16 MFMA pipeline.
//   h1 = relu([aggr(x)|x] @ [w1l;w1r] + b1)      (MFMA, K=256)
//   h2 = relu([aggr(h1)|h1] @ [w2l;w2r] + b2)
//   out = log_softmax(mean_pool(h2) @ wf + bf)
// R1: atomics -> CSR+gather. R2: bf16 MFMA GEMM, packed weights.
// R3: gather MLP. R4: atomic-free localized CSR fill. R5: segmented pool.
// R6: fused layer REGRESSED (occupancy collapse) -> reverted.
// R7: column-class gather REGRESSED per-kernel (csr re-read, VALU-bound)
//     -> reverted.
// R8: uint4 gather: 16 lanes/row, 4 edge slots, mask-free main loop,
//     csr prefetch. Same 64B/lane in flight as R5 at 2.7x fewer vmem instrs.
// ---------------------------------------------------------------------------

#define FDIM 128

typedef __attribute__((ext_vector_type(8))) short bf16x8;
typedef __attribute__((ext_vector_type(4))) float f32x4;

__device__ inline unsigned short f2bf(float f) {
    union { float f; unsigned u; } v; v.f = f;
    unsigned r = v.u + 0x7fff + ((v.u >> 16) & 1);   // RNE
    return (unsigned short)(r >> 16);
}
__device__ inline float bf2f(unsigned short b) {
    union { unsigned u; float f; } v; v.u = ((unsigned)b) << 16;
    return v.f;
}

// unpack uint4 (8 bf16) and accumulate into 8 f32
__device__ inline void acc8(float* a, uint4 w) {
    union { unsigned u; float f; } t;
    t.u = w.x << 16;          a[0] += t.f;
    t.u = w.x & 0xffff0000u;  a[1] += t.f;
    t.u = w.y << 16;          a[2] += t.f;
    t.u = w.y & 0xffff0000u;  a[3] += t.f;
    t.u = w.z << 16;          a[4] += t.f;
    t.u = w.z & 0xffff0000u;  a[5] += t.f;
    t.u = w.w << 16;          a[6] += t.f;
    t.u = w.w & 0xffff0000u;  a[7] += t.f;
}
__device__ inline void acc8m(float* a, uint4 w, float m) {
    union { unsigned u; float f; } t;
    t.u = w.x << 16;          a[0] = fmaf(m, t.f, a[0]);
    t.u = w.x & 0xffff0000u;  a[1] = fmaf(m, t.f, a[1]);
    t.u = w.y << 16;          a[2] = fmaf(m, t.f, a[2]);
    t.u = w.y & 0xffff0000u;  a[3] = fmaf(m, t.f, a[3]);
    t.u = w.z << 16;          a[4] = fmaf(m, t.f, a[4]);
    t.u = w.z & 0xffff0000u;  a[5] = fmaf(m, t.f, a[5]);
    t.u = w.w << 16;          a[6] = fmaf(m, t.f, a[6]);
    t.u = w.w & 0xffff0000u;  a[7] = fmaf(m, t.f, a[7]);
}

// --- merged prep: deg+rank | f32->bf16 cvt | weight packs -------------------
__global__ __launch_bounds__(256) void prep_k(
        const int* __restrict__ dst, int* __restrict__ deg, int* __restrict__ rank, int nE,
        const float* __restrict__ x, unsigned short* __restrict__ xb, int n4,
        const float* __restrict__ w1l, const float* __restrict__ w1r,
        unsigned short* __restrict__ wp1,
        const float* __restrict__ w2l, const float* __restrict__ w2r,
        unsigned short* __restrict__ wp2,
        int nbE, int nbC) {
    int bid = blockIdx.x, tid = threadIdx.x;
    if (bid < nbE) {
        int e = bid * 256 + tid;
        if (e < nE) rank[e] = atomicAdd(&deg[dst[e]], 1);
    } else if (bid < nbE + nbC) {
        int i = (bid - nbE) * 256 + tid;
        if (i < n4) {
            float4 v = ((const float4*)x)[i];
            ushort4 o;
            o.x = f2bf(v.x); o.y = f2bf(v.y); o.z = f2bf(v.z); o.w = f2bf(v.w);
            ((ushort4*)xb)[i] = o;
        }
    } else {
        int pb = bid - nbE - nbC;                 // 0..31
        const float* wl = (pb < 16) ? w1l : w2l;
        const float* wr = (pb < 16) ? w1r : w2r;
        unsigned short* wp = (pb < 16) ? wp1 : wp2;
        int t = (pb & 15) * 256 + tid;            // 0..4095
        int lane = t & 63, s = (t >> 6) & 7, nt = t >> 9;
        int kbase = s * 32 + ((lane >> 4) * 8);
        int c = nt * 16 + (lane & 15);
        unsigned short tmp[8];
        #pragma unroll
        for (int j = 0; j < 8; ++j) {
            int k = kbase + j;
            float w = (k < 128) ? wl[k * 128 + c] : wr[(k - 128) * 128 + c];
            tmp[j] = f2bf(w);
        }
        ushort4 lo, hi;
        lo.x = tmp[0]; lo.y = tmp[1]; lo.z = tmp[2]; lo.w = tmp[3];
        hi.x = tmp[4]; hi.y = tmp[5]; hi.z = tmp[6]; hi.w = tmp[7];
        ((ushort4*)wp)[t * 2 + 0] = lo;
        ((ushort4*)wp)[t * 2 + 1] = hi;
    }
}

__global__ __launch_bounds__(256) void scan1_k(const int* __restrict__ deg,
                                               int* __restrict__ rowstart,
                                               int* __restrict__ bsum, int n) {
    __shared__ int s[256];
    int tid = threadIdx.x;
    int i = blockIdx.x * 256 + tid;
    int v = (i < n) ? deg[i] : 0;
    s[tid] = v;
    __syncthreads();
    for (int off = 1; off < 256; off <<= 1) {
        int t = (tid >= off) ? s[tid - off] : 0;
        __syncthreads();
        s[tid] += t;
        __syncthreads();
    }
    if (i < n) rowstart[i] = s[tid] - v;
    if (tid == 255) bsum[blockIdx.x] = s[255];
}

__global__ __launch_bounds__(256) void scan2_k(int* __restrict__ bsum, int nb) {
    __shared__ int s[256];
    int tid = threadIdx.x;
    int v = (tid < nb) ? bsum[tid] : 0;
    s[tid] = v;
    __syncthreads();
    for (int off = 1; off < 256; off <<= 1) {
        int t = (tid >= off) ? s[tid - off] : 0;
        __syncthreads();
        s[tid] += t;
        __syncthreads();
    }
    if (tid < nb) bsum[tid] = s[tid] - v;
}

__global__ void addoff_k(int* __restrict__ rowstart, const int* __restrict__ bsum, int n) {
    int i = blockIdx.x * blockDim.x + threadIdx.x;
    if (i < n) rowstart[i] += bsum[blockIdx.x];
}

// --- atomic-free CSR fill, class-partitioned by node range -----------------
__global__ __launch_bounds__(256) void fill_swz_k(
        const int* __restrict__ src, const int* __restrict__ dst,
        const int* __restrict__ rowstart, const int* __restrict__ rank,
        int* __restrict__ csr, int nE, int rngSize) {
    int cls = blockIdx.x & 7;
    int lo = cls * rngSize, hi = lo + rngSize;
    int nb = gridDim.x >> 3;
    int bi = blockIdx.x >> 3;
    for (int e = bi * 256 + threadIdx.x; e < nE; e += nb * 256) {
        int d = dst[e];
        if (d >= lo && d < hi)
            csr[rowstart[d] + rank[e]] = src[e];
    }
}

// --- uint4 gather-mean: one wave per node ----------------------------------
// lane = (edge slot es 0..3) x (col slot cs 0..15, 16B each -> 256B row).
// Main loop: 16 edges/iter, NO masking, 4 x uint4 feat loads (64B/lane in
// flight) + next iter's csr prefetched. Tail: single masked 16-slot pass.
__global__ __launch_bounds__(256) void gather_v4_k(
        const uint4* __restrict__ feat,           // [n][16] uint4 (256B rows)
        const int* __restrict__ csr, const int* __restrict__ rowstart,
        const int* __restrict__ deg, uint4* __restrict__ outr, int n) {
    int node = blockIdx.x * 4 + (threadIdx.x >> 6);
    if (node >= n) return;
    int lane = threadIdx.x & 63;
    int es = lane >> 4;                           // edge slot
    int cs = lane & 15;                           // uint4 col slot
    int s0 = rowstart[node], dc = deg[node];

    float acc[8] = {0.f, 0.f, 0.f, 0.f, 0.f, 0.f, 0.f, 0.f};
    int base = 0;
    int i0 = 0, i1 = 0, i2 = 0, i3 = 0;
    if (base + 16 <= dc) {
        i0 = csr[s0 + es];
        i1 = csr[s0 + 4 + es];
        i2 = csr[s0 + 8 + es];
        i3 = csr[s0 + 12 + es];
    }
    while (base + 16 <= dc) {
        uint4 w0 = feat[(size_t)i0 * 16 + cs];
        uint4 w1 = feat[(size_t)i1 * 16 + cs];
        uint4 w2 = feat[(size_t)i2 * 16 + cs];
        uint4 w3 = feat[(size_t)i3 * 16 + cs];
        base += 16;
        if (base + 16 <= dc) {                    // prefetch next indices
            i0 = csr[s0 + base + es];
            i1 = csr[s0 + base + 4 + es];
            i2 = csr[s0 + base + 8 + es];
            i3 = csr[s0 + base + 12 + es];
        }
        acc8(acc, w0);
        acc8(acc, w1);
        acc8(acc, w2);
        acc8(acc, w3);
    }
    if (base < dc) {                              // masked tail
        int c = dc - 1;
        int e0 = base + es, e1 = base + 4 + es, e2 = base + 8 + es, e3 = base + 12 + es;
        int t0 = csr[s0 + min(e0, c)];
        int t1 = csr[s0 + min(e1, c)];
        int t2 = csr[s0 + min(e2, c)];
        int t3 = csr[s0 + min(e3, c)];
        uint4 w0 = feat[(size_t)t0 * 16 + cs];
        uint4 w1 = feat[(size_t)t1 * 16 + cs];
        uint4 w2 = feat[(size_t)t2 * 16 + cs];
        uint4 w3 = feat[(size_t)t3 * 16 + cs];
        acc8m(acc, w0, (e0 < dc) ? 1.0f : 0.0f);
        acc8m(acc, w1, (e1 < dc) ? 1.0f : 0.0f);
        acc8m(acc, w2, (e2 < dc) ? 1.0f : 0.0f);
        acc8m(acc, w3, (e3 < dc) ? 1.0f : 0.0f);
    }

    // reduce across the 4 edge slots (lane bits 4,5)
    #pragma unroll
    for (int k = 0; k < 8; ++k) {
        acc[k] += __shfl_xor(acc[k], 16, 64);
        acc[k] += __shfl_xor(acc[k], 32, 64);
    }

    if (es == 0) {
        float inv = (dc > 0) ? 1.0f / (float)dc : 0.0f;
        uint4 o;
        o.x = ((unsigned)f2bf(acc[1] * inv) << 16) | (unsigned)f2bf(acc[0] * inv);
        o.y = ((unsigned)f2bf(acc[3] * inv) << 16) | (unsigned)f2bf(acc[2] * inv);
        o.z = ((unsigned)f2bf(acc[5] * inv) << 16) | (unsigned)f2bf(acc[4] * inv);
        o.w = ((unsigned)f2bf(acc[7] * inv) << 16) | (unsigned)f2bf(acc[6] * inv);
        outr[(size_t)node * 16 + cs] = o;
    }
}

// --- fused SAGE GEMM: out = relu([A|R] @ Wpack + bias), bf16 MFMA ----------
__global__ __launch_bounds__(256) void gemm_mfma_k(
        const unsigned short* __restrict__ A,     // aggr [n][128] bf16
        const unsigned short* __restrict__ R,     // root [n][128] bf16
        const unsigned short* __restrict__ wp,    // packed weights
        const float* __restrict__ bias,           // [128] f32
        unsigned short* __restrict__ outp,        // [n][128] bf16
        int n) {
    int tid = threadIdx.x;
    int wave = tid >> 6, lane = tid & 63;
    int rowTile = blockIdx.x * 64 + wave * 16;
    int lrow = lane & 15, lk = lane >> 4;

    int arow = rowTile + lrow;
    if (arow >= n) arow = n - 1;                  // clamp; stores are guarded

    bf16x8 a[8];
    const unsigned short* abase = A + (size_t)arow * FDIM + lk * 8;
    const unsigned short* rbase = R + (size_t)arow * FDIM + lk * 8;
    #pragma unroll
    for (int s = 0; s < 4; ++s) a[s] = *(const bf16x8*)(abase + s * 32);
    #pragma unroll
    for (int s = 0; s < 4; ++s) a[4 + s] = *(const bf16x8*)(rbase + s * 32);

    const bf16x8* bp = (const bf16x8*)wp;
    int ocol = lane & 15;
    int orow0 = rowTile + (lane >> 4) * 4;

    #pragma unroll
    for (int nt = 0; nt < 8; ++nt) {
        float bv = bias[nt * 16 + ocol];
        f32x4 acc = {bv, bv, bv, bv};
        #pragma unroll
        for (int s = 0; s < 8; ++s) {
            bf16x8 b = bp[(nt * 8 + s) * 64 + lane];
            acc = __builtin_amdgcn_mfma_f32_16x16x32_bf16(a[s], b, acc, 0, 0, 0);
        }
        #pragma unroll
        for (int r = 0; r < 4; ++r) {
            int orow = orow0 + r;
            if (orow < n) {
                float v = fmaxf(acc[r], 0.0f);
                outp[(size_t)orow * FDIM + nt * 16 + ocol] = f2bf(v);
            }
        }
    }
}

// --- segmented global mean pool: 64 nodes/block, batch sorted --------------
__global__ __launch_bounds__(256) void pool_seg_k(
        const unsigned short* __restrict__ h,     // [nN][128] bf16
        const int* __restrict__ batch,
        float* __restrict__ gsum, int* __restrict__ gcnt, int nN) {
    __shared__ int bw[64];
    __shared__ float red[8][32][4];
    int base = blockIdx.x * 64;
    if (base >= nN) return;
    int tid = threadIdx.x;
    int rg = tid >> 5, cs = tid & 31;
    int cnt = min(64, nN - base);
    if (tid < 64) bw[tid] = batch[min(base + tid, nN - 1)];
    __syncthreads();
    int g0 = bw[0], g1 = bw[cnt - 1];

    for (int g = g0; g <= g1; ++g) {
        int s = 0;
        while (s < cnt && bw[s] < g) ++s;
        int e = s;
        while (e < cnt && bw[e] == g) ++e;

        float a0 = 0.f, a1 = 0.f, a2 = 0.f, a3 = 0.f;
        for (int i = s + rg; i < e; i += 8) {
            uint2 v = ((const uint2*)(h + (size_t)(base + i) * FDIM))[cs];
            a0 += bf2f((unsigned short)(v.x & 0xffff));
            a1 += bf2f((unsigned short)(v.x >> 16));
            a2 += bf2f((unsigned short)(v.y & 0xffff));
            a3 += bf2f((unsigned short)(v.y >> 16));
        }
        red[rg][cs][0] = a0; red[rg][cs][1] = a1;
        red[rg][cs][2] = a2; red[rg][cs][3] = a3;
        __syncthreads();
        if (rg == 0 && e > s) {
            #pragma unroll
            for (int r = 1; r < 8; ++r) {
                a0 += red[r][cs][0]; a1 += red[r][cs][1];
                a2 += red[r][cs][2]; a3 += red[r][cs][3];
            }
            float* go = gsum + (size_t)g * FDIM + cs * 4;
            atomicAdd(go + 0, a0);
            atomicAdd(go + 1, a1);
            atomicAdd(go + 2, a2);
            atomicAdd(go + 3, a3);
            if (cs == 0) atomicAdd(&gcnt[g], e - s);
        }
        __syncthreads();
    }
}

// --- head: logits = mean @ wf + bf ; log_softmax ---------------------------
__global__ __launch_bounds__(128) void head_k(const float* __restrict__ gsum,
                                              const int* __restrict__ gcnt,
                                              const float* __restrict__ wf,
                                              const float* __restrict__ bf,
                                              float* __restrict__ out, int nG) {
    int g = blockIdx.x;
    if (g >= nG) return;
    __shared__ float row[FDIM];
    int tid = threadIdx.x;
    float inv = 1.0f / fmaxf((float)gcnt[g], 1.0f);
    row[tid] = gsum[(size_t)g * FDIM + tid] * inv;
    __syncthreads();

    float logit = -1e30f;
    if (tid < 16) {
        logit = bf[tid];
        for (int k = 0; k < FDIM; ++k) logit += row[k] * wf[k * 16 + tid];
    }
    float m = logit;
    for (int off = 8; off >= 1; off >>= 1) m = fmaxf(m, __shfl_xor(m, off, 64));
    float ev = (tid < 16) ? expf(logit - m) : 0.0f;
    float sum = ev;
    for (int off = 8; off >= 1; off >>= 1) sum += __shfl_xor(sum, off, 64);
    if (tid < 16) out[(size_t)g * 16 + tid] = logit - m - logf(sum);
}

extern "C" void kernel_launch(void* const* d_in, const int* in_sizes, int n_in,
                              void* d_out, int out_size, void* d_ws, size_t ws_size,
                              hipStream_t stream) {
    const float* x    = (const float*)d_in[0];
    const int*   ei   = (const int*)d_in[1];
    const int*   batch= (const int*)d_in[2];
    const float* w1l  = (const float*)d_in[3];
    const float* b1   = (const float*)d_in[4];
    const float* w1r  = (const float*)d_in[5];
    const float* w2l  = (const float*)d_in[6];
    const float* b2   = (const float*)d_in[7];
    const float* w2r  = (const float*)d_in[8];
    const float* wf   = (const float*)d_in[9];
    const float* bf   = (const float*)d_in[10];
    float* out = (float*)d_out;

    const int N = in_sizes[0] / FDIM;
    const int E = in_sizes[1] / 2;
    const int G = out_size / 16;
    const int* src = ei;
    const int* dst = ei + E;
    const int NB = (N + 255) / 256;              // <= 256 for scan2_k

    // --- workspace layout ---
    char* ws = (char*)d_ws;
    size_t off = 0;
    auto alloc = [&](size_t bytes) { void* p = ws + off; off = (off + bytes + 255) & ~(size_t)255; return p; };
    unsigned short* xb   = (unsigned short*)alloc((size_t)N * FDIM * 2); // also h2
    unsigned short* aggr = (unsigned short*)alloc((size_t)N * FDIM * 2);
    unsigned short* h1   = (unsigned short*)alloc((size_t)N * FDIM * 2);
    unsigned short* wp1  = (unsigned short*)alloc(8 * 8 * 64 * 8 * 2);
    unsigned short* wp2  = (unsigned short*)alloc(8 * 8 * 64 * 8 * 2);
    int* deg      = (int*)alloc((size_t)N * sizeof(int));
    int* rowstart = (int*)alloc((size_t)N * sizeof(int));
    int* bsum     = (int*)alloc(256 * sizeof(int));
    int* csr      = (int*)alloc((size_t)E * sizeof(int));
    int* rank     = (int*)alloc((size_t)E * sizeof(int));
    float* gsum   = (float*)alloc((size_t)G * FDIM * sizeof(float));
    int*   gcnt   = (int*)alloc((size_t)G * sizeof(int));
    unsigned short* h2 = xb;                      // xb dead once h2 is written

    // --- zero accumulators ---
    hipMemsetAsync(deg, 0, (size_t)N * sizeof(int), stream);
    hipMemsetAsync(gsum, 0, (size_t)G * FDIM * sizeof(float), stream);
    hipMemsetAsync(gcnt, 0, (size_t)G * sizeof(int), stream);

    // --- merged prep: deg/rank | cvt | packs ---
    const int nbE = (E + 255) / 256;
    const int nbC = (N * FDIM / 4 + 255) / 256;
    prep_k<<<nbE + nbC + 32, 256, 0, stream>>>(dst, deg, rank, E,
                                               x, xb, N * FDIM / 4,
                                               w1l, w1r, wp1, w2l, w2r, wp2,
                                               nbE, nbC);

    // --- CSR offsets + localized fill ---
    scan1_k<<<NB, 256, 0, stream>>>(deg, rowstart, bsum, N);
    scan2_k<<<1, 256, 0, stream>>>(bsum, NB);
    addoff_k<<<NB, 256, 0, stream>>>(rowstart, bsum, N);
    {
        int rngSize = (N + 7) / 8;
        fill_swz_k<<<2048, 256, 0, stream>>>(src, dst, rowstart, rank, csr, E, rngSize);
    }

    // --- layer 1 ---
    gather_v4_k<<<(N + 3) / 4, 256, 0, stream>>>((const uint4*)xb, csr, rowstart, deg,
                                                 (uint4*)aggr, N);
    gemm_mfma_k<<<(N + 63) / 64, 256, 0, stream>>>(aggr, xb, wp1, b1, h1, N);

    // --- layer 2 ---
    gather_v4_k<<<(N + 3) / 4, 256, 0, stream>>>((const uint4*)h1, csr, rowstart, deg,
                                                 (uint4*)aggr, N);
    gemm_mfma_k<<<(N + 63) / 64, 256, 0, stream>>>(aggr, h1, wp2, b2, h2, N);

    // --- pool + head ---
    pool_seg_k<<<(N + 63) / 64, 256, 0, stream>>>(h2, batch, gsum, gcnt, N);
    head_k<<<G, 128, 0, stream>>>(gsum, gcnt, wf, bf, out, G);
}